// Round 4
// baseline (248.455 us; speedup 1.0000x reference)
//
#include <hip/hip_runtime.h>

// YOLO loss forward on MI355X. input/target: (B=256,C=25,S=64,S=64) fp32.
// R4: R1-R3 all plateau at ~82us (2.7 TB/s) regardless of occupancy, MLP,
// or HBM-vs-L3 source -> the plane-hopping access pattern is the cap.
// Rewrite as a pure streaming sweep: g walks both arrays sequentially,
// channel c=(g>>10)%25 is wave-uniform. Channel-separable terms (24/25 of
// data) need only (p,t,mask); the confidence/IoU term (c==4, 1/25 of waves)
// gathers ch0-3 of both tensors. Mask gathers hit L2/L3 (4MB plane reused
// 24x within the sweep window).

#define COORD 5.0f
#define NOOBJ 0.5f

constexpr int B = 256;
constexpr int S = 64;
constexpr int SS = S * S;                       // 4096
constexpr int CH4 = SS / 4;                     // 1024 float4 per plane
constexpr int NF4 = B * 25 * CH4;               // 6,553,600 float4 per array
constexpr int THREADS = 256;
constexpr int ITERS = 4;
constexpr int BLOCKS = NF4 / (THREADS * ITERS); // 6400

__global__ void zero_out_kernel(float* out) { out[0] = 0.0f; }

__device__ __forceinline__ float conf_term(float px, float py, float pw, float ph,
                                           float tx, float ty, float tw, float th,
                                           float pc, float tc) {
    const float inv = 1.0f / 64.0f;
    const float m = (tc > 0.0f) ? 1.0f : 0.0f;
    const float c1x = px * inv, c1y = py * inv;
    const float c2x = tx * inv, c2y = ty * inv;
    const float dx = fminf(c1x + pw * 0.5f, c2x + tw * 0.5f)
                   - fmaxf(c1x - pw * 0.5f, c2x - tw * 0.5f);
    const float dy = fminf(c1y + ph * 0.5f, c2y + th * 0.5f)
                   - fmaxf(c1y - ph * 0.5f, c2y - th * 0.5f);
    const float inter = dx * dy;
    const float uni = pw * ph + tw * th - inter;
    const bool pos = (dx > 0.0f) && (dy > 0.0f);
    const float iou = pos ? (inter / uni) : 0.0f;
    const float e = pc - iou;
    return m * e * e + NOOBJ * (1.0f - m) * pc * pc;
}

__global__ __launch_bounds__(256) void yolo_loss_kernel(
        const float4* __restrict__ in, const float4* __restrict__ tg,
        float* __restrict__ out) {
    float acc = 0.0f;

    #pragma unroll
    for (int it = 0; it < ITERS; ++it) {
        const int g = (it * BLOCKS + (int)blockIdx.x) * THREADS + (int)threadIdx.x;
        const int plane = g >> 10;          // [0, 6400), wave-uniform
        const int pp = g & 1023;
        const int b = plane / 25;           // wave-uniform (magic-mul)
        const int c = plane - b * 25;       // wave-uniform

        const float4 p = in[g];             // pure streaming
        const float4 t = tg[g];             // pure streaming

        if (c == 4) {
            // t IS the mask source; gather ch0..3 of both tensors for IoU.
            const int base0 = ((b * 25) << 10) | pp;
            const float4 p0 = in[base0 + 0 * CH4];
            const float4 p1 = in[base0 + 1 * CH4];
            const float4 p2 = in[base0 + 2 * CH4];
            const float4 p3 = in[base0 + 3 * CH4];
            const float4 t0 = tg[base0 + 0 * CH4];
            const float4 t1 = tg[base0 + 1 * CH4];
            const float4 t2 = tg[base0 + 2 * CH4];
            const float4 t3 = tg[base0 + 3 * CH4];
            acc += conf_term(p0.x, p1.x, p2.x, p3.x, t0.x, t1.x, t2.x, t3.x, p.x, t.x);
            acc += conf_term(p0.y, p1.y, p2.y, p3.y, t0.y, t1.y, t2.y, t3.y, p.y, t.y);
            acc += conf_term(p0.z, p1.z, p2.z, p3.z, t0.z, t1.z, t2.z, t3.z, p.z, t.z);
            acc += conf_term(p0.w, p1.w, p2.w, p3.w, t0.w, t1.w, t2.w, t3.w, p.w, t.w);
        } else {
            // channel-separable term: weight * m * (f(p)-f(t))^2
            const int mbase = ((b * 25 + 4) << 10) | pp;
            const float4 mk = tg[mbase];            // L2/L3-hot gather
            const float w = (c < 4) ? COORD : 1.0f;
            const bool dos = (c == 2) || (c == 3);  // sqrt channels
            float pv[4] = {p.x, p.y, p.z, p.w};
            float tv[4] = {t.x, t.y, t.z, t.w};
            const float mv[4] = {mk.x > 0.0f ? 1.0f : 0.0f,
                                 mk.y > 0.0f ? 1.0f : 0.0f,
                                 mk.z > 0.0f ? 1.0f : 0.0f,
                                 mk.w > 0.0f ? 1.0f : 0.0f};
            #pragma unroll
            for (int k = 0; k < 4; ++k) {
                float a = pv[k], bb = tv[k];
                if (dos) { a = sqrtf(a); bb = sqrtf(bb); }
                const float d = a - bb;
                acc += w * mv[k] * d * d;
            }
        }
    }

    // wave64 reduce -> LDS -> one atomic per block
    #pragma unroll
    for (int off = 32; off > 0; off >>= 1)
        acc += __shfl_down(acc, off, 64);

    __shared__ float smem[4];
    const int lane = threadIdx.x & 63;
    const int wid = threadIdx.x >> 6;
    if (lane == 0) smem[wid] = acc;
    __syncthreads();
    if (threadIdx.x == 0) {
        const float s = smem[0] + smem[1] + smem[2] + smem[3];
        atomicAdd(out, s);
    }
}

extern "C" void kernel_launch(void* const* d_in, const int* in_sizes, int n_in,
                              void* d_out, int out_size, void* d_ws, size_t ws_size,
                              hipStream_t stream) {
    const float4* in = (const float4*)d_in[0];
    const float4* tg = (const float4*)d_in[1];
    float* out = (float*)d_out;

    // d_out is re-poisoned to 0xAA before every timed launch -> zero it first.
    zero_out_kernel<<<1, 1, 0, stream>>>(out);

    yolo_loss_kernel<<<BLOCKS, THREADS, 0, stream>>>(in, tg, out);
}

// Round 5
// 244.234 us; speedup vs baseline: 1.0173x; 1.0173x over previous
//
#include <hip/hip_runtime.h>

// YOLO loss forward on MI355X. input/target: (B=256,C=25,S=64,S=64) fp32.
// R5: R1-R4 establish a ~2.7 TB/s fill-path cap (independent of occupancy,
// MLP, and HBM-vs-L3 source). R2 structure was fastest (82us). This round:
// R2 + non-temporal (no-allocate) loads on all stream-once data, normal
// load only for the 5x-reused mask plane t4. If neutral, we're at the
// structural roofline (210 MB / 2.7 TB/s = 78us).

#define COORD 5.0f
#define NOOBJ 0.5f

constexpr int B = 256;
constexpr int S = 64;
constexpr int SS = S * S;                     // 4096
constexpr int CH_STRIDE4 = SS / 4;            // 1024 float4 per channel plane
constexpr int IMG_STRIDE4 = 25 * CH_STRIDE4;  // 25600 float4 per image
constexpr int NPOS4 = B * SS / 4;             // 262144 float4-groups
constexpr int BLOCKS_PER_GROUP = NPOS4 / 256; // 1024
constexpr int NGROUPS = 5;                    // 1 box group + 4 class groups

typedef float vfloat4 __attribute__((ext_vector_type(4)));

__device__ __forceinline__ float4 ntload(const float4* p) {
    vfloat4 v = __builtin_nontemporal_load((const vfloat4*)p);
    return make_float4(v.x, v.y, v.z, v.w);
}

__global__ void zero_out_kernel(float* out) { out[0] = 0.0f; }

__global__ __launch_bounds__(256) void yolo_loss_kernel(
        const float4* __restrict__ in, const float4* __restrict__ tg,
        float* __restrict__ out) {
    const int group = blockIdx.x % NGROUPS;          // wave-uniform
    const int chunk = blockIdx.x / NGROUPS;          // 0..1023
    const int gpos = (chunk << 8) | threadIdx.x;     // 0..262143
    const int b = gpos >> 10;
    const int pp = gpos & 1023;
    const int base = b * IMG_STRIDE4 + pp;

    float acc = 0.0f;

    if (group == 0) {
        // Box + confidence: channels 0..4 of both tensors.
        float4 p0 = ntload(&in[base + 0 * CH_STRIDE4]);
        float4 p1 = ntload(&in[base + 1 * CH_STRIDE4]);
        float4 p2 = ntload(&in[base + 2 * CH_STRIDE4]);
        float4 p3 = ntload(&in[base + 3 * CH_STRIDE4]);
        float4 p4 = ntload(&in[base + 4 * CH_STRIDE4]);
        float4 t0 = ntload(&tg[base + 0 * CH_STRIDE4]);
        float4 t1 = ntload(&tg[base + 1 * CH_STRIDE4]);
        float4 t2 = ntload(&tg[base + 2 * CH_STRIDE4]);
        float4 t3 = ntload(&tg[base + 3 * CH_STRIDE4]);
        float4 t4 = tg[base + 4 * CH_STRIDE4];   // mask plane: reused 5x, allocate

        const float invBlocks = 1.0f / (float)S;
        float px4[4] = {p0.x, p0.y, p0.z, p0.w};
        float py4[4] = {p1.x, p1.y, p1.z, p1.w};
        float pw4[4] = {p2.x, p2.y, p2.z, p2.w};
        float ph4[4] = {p3.x, p3.y, p3.z, p3.w};
        float pc4[4] = {p4.x, p4.y, p4.z, p4.w};
        float tx4[4] = {t0.x, t0.y, t0.z, t0.w};
        float ty4[4] = {t1.x, t1.y, t1.z, t1.w};
        float tw4[4] = {t2.x, t2.y, t2.z, t2.w};
        float th4[4] = {t3.x, t3.y, t3.z, t3.w};
        float tc4[4] = {t4.x, t4.y, t4.z, t4.w};

        #pragma unroll
        for (int k = 0; k < 4; ++k) {
            const float px = px4[k], py = py4[k], pw = pw4[k], ph = ph4[k];
            const float pc = pc4[k];
            const float tx = tx4[k], ty = ty4[k], tw = tw4[k], th = th4[k];
            const float m = (tc4[k] > 0.0f) ? 1.0f : 0.0f;

            const float c1x = px * invBlocks, c1y = py * invBlocks;
            const float c2x = tx * invBlocks, c2y = ty * invBlocks;
            const float x1a = c1x - pw * 0.5f, x2a = c1x + pw * 0.5f;
            const float y1a = c1y - ph * 0.5f, y2a = c1y + ph * 0.5f;
            const float x1b = c2x - tw * 0.5f, x2b = c2x + tw * 0.5f;
            const float y1b = c2y - th * 0.5f, y2b = c2y + th * 0.5f;
            const float dx = fminf(x2a, x2b) - fmaxf(x1a, x1b);
            const float dy = fminf(y2a, y2b) - fmaxf(y1a, y1b);
            const float inter = dx * dy;
            const float uni = pw * ph + tw * th - inter;
            const bool pos = (dx > 0.0f) && (dy > 0.0f);
            const float iou = pos ? (inter / uni) : 0.0f;

            const float ex = px - tx, ey = py - ty;
            acc += COORD * m * (ex * ex + ey * ey);
            const float sw = sqrtf(pw) - sqrtf(tw);
            const float sh = sqrtf(ph) - sqrtf(th);
            acc += COORD * m * (sw * sw + sh * sh);
            const float ec = pc - iou;
            acc += m * ec * ec;
            acc += NOOBJ * (1.0f - m) * (pc * pc);
        }
    } else {
        // Class group: 5 channels starting at 5 + (group-1)*5, plus t4 mask.
        const int c0 = 5 + (group - 1) * 5;
        float4 t4 = tg[base + 4 * CH_STRIDE4];   // mask plane: reused 5x, allocate
        float4 pv0 = ntload(&in[base + (c0 + 0) * CH_STRIDE4]);
        float4 pv1 = ntload(&in[base + (c0 + 1) * CH_STRIDE4]);
        float4 pv2 = ntload(&in[base + (c0 + 2) * CH_STRIDE4]);
        float4 pv3 = ntload(&in[base + (c0 + 3) * CH_STRIDE4]);
        float4 pv4 = ntload(&in[base + (c0 + 4) * CH_STRIDE4]);
        float4 tv0 = ntload(&tg[base + (c0 + 0) * CH_STRIDE4]);
        float4 tv1 = ntload(&tg[base + (c0 + 1) * CH_STRIDE4]);
        float4 tv2 = ntload(&tg[base + (c0 + 2) * CH_STRIDE4]);
        float4 tv3 = ntload(&tg[base + (c0 + 3) * CH_STRIDE4]);
        float4 tv4 = ntload(&tg[base + (c0 + 4) * CH_STRIDE4]);

        const float m0 = (t4.x > 0.0f) ? 1.0f : 0.0f;
        const float m1 = (t4.y > 0.0f) ? 1.0f : 0.0f;
        const float m2 = (t4.z > 0.0f) ? 1.0f : 0.0f;
        const float m3 = (t4.w > 0.0f) ? 1.0f : 0.0f;
        float a0 = 0.0f, a1 = 0.0f, a2 = 0.0f, a3 = 0.0f;
        float d;
        d = pv0.x - tv0.x; a0 += d * d;
        d = pv0.y - tv0.y; a1 += d * d;
        d = pv0.z - tv0.z; a2 += d * d;
        d = pv0.w - tv0.w; a3 += d * d;
        d = pv1.x - tv1.x; a0 += d * d;
        d = pv1.y - tv1.y; a1 += d * d;
        d = pv1.z - tv1.z; a2 += d * d;
        d = pv1.w - tv1.w; a3 += d * d;
        d = pv2.x - tv2.x; a0 += d * d;
        d = pv2.y - tv2.y; a1 += d * d;
        d = pv2.z - tv2.z; a2 += d * d;
        d = pv2.w - tv2.w; a3 += d * d;
        d = pv3.x - tv3.x; a0 += d * d;
        d = pv3.y - tv3.y; a1 += d * d;
        d = pv3.z - tv3.z; a2 += d * d;
        d = pv3.w - tv3.w; a3 += d * d;
        d = pv4.x - tv4.x; a0 += d * d;
        d = pv4.y - tv4.y; a1 += d * d;
        d = pv4.z - tv4.z; a2 += d * d;
        d = pv4.w - tv4.w; a3 += d * d;
        acc = m0 * a0 + m1 * a1 + m2 * a2 + m3 * a3;
    }

    // wave64 reduce -> LDS -> one atomic per block
    #pragma unroll
    for (int off = 32; off > 0; off >>= 1)
        acc += __shfl_down(acc, off, 64);

    __shared__ float smem[4];
    const int lane = threadIdx.x & 63;
    const int wid = threadIdx.x >> 6;
    if (lane == 0) smem[wid] = acc;
    __syncthreads();
    if (threadIdx.x == 0) {
        const float s = smem[0] + smem[1] + smem[2] + smem[3];
        atomicAdd(out, s);
    }
}

extern "C" void kernel_launch(void* const* d_in, const int* in_sizes, int n_in,
                              void* d_out, int out_size, void* d_ws, size_t ws_size,
                              hipStream_t stream) {
    const float4* in = (const float4*)d_in[0];
    const float4* tg = (const float4*)d_in[1];
    float* out = (float*)d_out;

    // d_out is re-poisoned to 0xAA before every timed launch -> zero it first.
    zero_out_kernel<<<1, 1, 0, stream>>>(out);

    const int threads = 256;
    const int blocks = BLOCKS_PER_GROUP * NGROUPS;  // 5120
    yolo_loss_kernel<<<blocks, threads, 0, stream>>>(in, tg, out);
}

// Round 6
// 226.037 us; speedup vs baseline: 1.0992x; 1.0805x over previous
//
#include <hip/hip_runtime.h>
#include <stdint.h>

// YOLO loss forward on MI355X. input/target: (B=256,C=25,S=64,S=64) fp32.
// R6: R1-R5 pin a ~2.7 TB/s read-delivery cap (4.4 B/cy/CU) independent of
// occupancy, MLP, nt-hints, and HBM-vs-L3 residency -> suspect the CU-side
// VGPR load-return path (L1 MSHR-limited). m97's GEMM sustained ~22 B/cy/CU
// via the global_load_lds TA->LDS DMA path. This round: route ALL global
// reads through __builtin_amdgcn_global_load_lds (16B/lane), stage 11
// channel planes per block into LDS, consume from LDS. If neutral, the cap
// is fabric-side and 78us = 210MB/2.7TB/s is the structural roofline.

#define COORD 5.0f
#define NOOBJ 0.5f

constexpr int B = 256;
constexpr int S = 64;
constexpr int SS = S * S;                     // 4096
constexpr int CH4 = SS / 4;                   // 1024 float4 per channel plane
constexpr int IMG4 = 25 * CH4;                // 25600 float4 per image
constexpr int NPOS4 = B * SS / 4;             // 262144
constexpr int BLOCKS_PER_GROUP = NPOS4 / 256; // 1024
constexpr int NGROUPS = 5;

typedef __attribute__((address_space(3))) uint32_t lds_u32;
typedef __attribute__((address_space(1))) const uint32_t gbl_u32;

__global__ void zero_out_kernel(float* out) { out[0] = 0.0f; }

__global__ __launch_bounds__(256) void yolo_loss_kernel(
        const float4* __restrict__ in, const float4* __restrict__ tg,
        float* __restrict__ out) {
    // 11 planes x 256 float4 = 44 KB staged per block.
    __shared__ float4 lds[11][256];

    const int group = blockIdx.x % NGROUPS;   // block-uniform
    const int chunk = blockIdx.x / NGROUPS;   // 0..1023
    const int tid = threadIdx.x;
    const int lane = tid & 63;
    const int wid = tid >> 6;
    const int b = chunk >> 2;                         // image
    const int ppb = (chunk & 3) << 8;                 // pp base of this block
    const int base = b * IMG4 + ppb;                  // block-uniform

    // Build the 11-plane source list (block-uniform).
    const float4* gsrc[11];
    if (group == 0) {
        #pragma unroll
        for (int c = 0; c < 5; ++c) {
            gsrc[c]     = in + base + c * CH4;
            gsrc[5 + c] = tg + base + c * CH4;
        }
        gsrc[10] = tg + base + 4 * CH4;  // duplicate of slot 9 (uniform CF)
    } else {
        const int c0 = 5 + (group - 1) * 5;
        #pragma unroll
        for (int j = 0; j < 5; ++j) {
            gsrc[j]     = in + base + (c0 + j) * CH4;
            gsrc[5 + j] = tg + base + (c0 + j) * CH4;
        }
        gsrc[10] = tg + base + 4 * CH4;  // mask plane
    }

    // Async TA->LDS staging: each wave issues 11 x 1KB DMA ops.
    // LDS dest must be wave-uniform base + lane*16 -> write wave wid's
    // 64 float4 at lds[j][wid*64 .. wid*64+63].
    const int woff = wid << 6;
    #pragma unroll
    for (int j = 0; j < 11; ++j) {
        const float4* gp = gsrc[j] + woff + lane;
        __builtin_amdgcn_global_load_lds((gbl_u32*)gp,
                                         (lds_u32*)&lds[j][woff],
                                         16, 0, 0);
    }
    __syncthreads();   // drains vmcnt; LDS now valid

    float acc = 0.0f;

    if (group == 0) {
        const float4 p0 = lds[0][tid], p1 = lds[1][tid], p2 = lds[2][tid];
        const float4 p3 = lds[3][tid], p4 = lds[4][tid];
        const float4 t0 = lds[5][tid], t1 = lds[6][tid], t2 = lds[7][tid];
        const float4 t3 = lds[8][tid], t4 = lds[9][tid];

        const float invBlocks = 1.0f / (float)S;
        float px4[4] = {p0.x, p0.y, p0.z, p0.w};
        float py4[4] = {p1.x, p1.y, p1.z, p1.w};
        float pw4[4] = {p2.x, p2.y, p2.z, p2.w};
        float ph4[4] = {p3.x, p3.y, p3.z, p3.w};
        float pc4[4] = {p4.x, p4.y, p4.z, p4.w};
        float tx4[4] = {t0.x, t0.y, t0.z, t0.w};
        float ty4[4] = {t1.x, t1.y, t1.z, t1.w};
        float tw4[4] = {t2.x, t2.y, t2.z, t2.w};
        float th4[4] = {t3.x, t3.y, t3.z, t3.w};
        float tc4[4] = {t4.x, t4.y, t4.z, t4.w};

        #pragma unroll
        for (int k = 0; k < 4; ++k) {
            const float px = px4[k], py = py4[k], pw = pw4[k], ph = ph4[k];
            const float pc = pc4[k];
            const float tx = tx4[k], ty = ty4[k], tw = tw4[k], th = th4[k];
            const float m = (tc4[k] > 0.0f) ? 1.0f : 0.0f;

            const float c1x = px * invBlocks, c1y = py * invBlocks;
            const float c2x = tx * invBlocks, c2y = ty * invBlocks;
            const float dx = fminf(c1x + pw * 0.5f, c2x + tw * 0.5f)
                           - fmaxf(c1x - pw * 0.5f, c2x - tw * 0.5f);
            const float dy = fminf(c1y + ph * 0.5f, c2y + th * 0.5f)
                           - fmaxf(c1y - ph * 0.5f, c2y - th * 0.5f);
            const float inter = dx * dy;
            const float uni = pw * ph + tw * th - inter;
            const bool pos = (dx > 0.0f) && (dy > 0.0f);
            const float iou = pos ? (inter / uni) : 0.0f;

            const float ex = px - tx, ey = py - ty;
            acc += COORD * m * (ex * ex + ey * ey);
            const float sw = sqrtf(pw) - sqrtf(tw);
            const float sh = sqrtf(ph) - sqrtf(th);
            acc += COORD * m * (sw * sw + sh * sh);
            const float ec = pc - iou;
            acc += m * ec * ec;
            acc += NOOBJ * (1.0f - m) * (pc * pc);
        }
    } else {
        const float4 t4 = lds[10][tid];
        const float m0 = (t4.x > 0.0f) ? 1.0f : 0.0f;
        const float m1 = (t4.y > 0.0f) ? 1.0f : 0.0f;
        const float m2 = (t4.z > 0.0f) ? 1.0f : 0.0f;
        const float m3 = (t4.w > 0.0f) ? 1.0f : 0.0f;
        float a0 = 0.0f, a1 = 0.0f, a2 = 0.0f, a3 = 0.0f;
        #pragma unroll
        for (int j = 0; j < 5; ++j) {
            const float4 pv = lds[j][tid];
            const float4 tv = lds[5 + j][tid];
            float d;
            d = pv.x - tv.x; a0 += d * d;
            d = pv.y - tv.y; a1 += d * d;
            d = pv.z - tv.z; a2 += d * d;
            d = pv.w - tv.w; a3 += d * d;
        }
        acc = m0 * a0 + m1 * a1 + m2 * a2 + m3 * a3;
    }

    // wave64 reduce -> LDS -> one atomic per block
    #pragma unroll
    for (int off = 32; off > 0; off >>= 1)
        acc += __shfl_down(acc, off, 64);

    __shared__ float smem[4];
    if (lane == 0) smem[wid] = acc;
    __syncthreads();
    if (tid == 0) {
        const float s = smem[0] + smem[1] + smem[2] + smem[3];
        atomicAdd(out, s);
    }
}

extern "C" void kernel_launch(void* const* d_in, const int* in_sizes, int n_in,
                              void* d_out, int out_size, void* d_ws, size_t ws_size,
                              hipStream_t stream) {
    const float4* in = (const float4*)d_in[0];
    const float4* tg = (const float4*)d_in[1];
    float* out = (float*)d_out;

    // d_out is re-poisoned to 0xAA before every timed launch -> zero it first.
    zero_out_kernel<<<1, 1, 0, stream>>>(out);

    const int threads = 256;
    const int blocks = BLOCKS_PER_GROUP * NGROUPS;  // 5120
    yolo_loss_kernel<<<blocks, threads, 0, stream>>>(in, tg, out);
}